// Round 1
// baseline (3895.727 us; speedup 1.0000x reference)
//
#include <hip/hip_runtime.h>

#define N_NODES 20000
#define N_EDGES 320000

__device__ __forceinline__ float sigm(float x) { return 1.0f / (1.0f + __expf(-x)); }
// jax.nn.gelu approximate=True: 0.5x(1+tanh(sqrt(2/pi)(x+0.044715x^3))) == x*sigmoid(2*sqrt(2/pi)*(x+0.044715x^3))
__device__ __forceinline__ float gelu(float x) {
    return x * sigm(1.5957691216057308f * (x + 0.044715f * x * x * x));
}

__global__ void init_kernel(const float* __restrict__ s0, const float* __restrict__ p0,
                            float* __restrict__ s, float* __restrict__ v) {
    int idx = blockIdx.x * 256 + threadIdx.x;
    if (idx < N_NODES * 16) s[idx] = s0[idx];
    if (idx < N_NODES * 3) v[idx] = p0[idx];
}

__global__ __launch_bounds__(256, 2) void edge_kernel(
    const float* __restrict__ s, const float* __restrict__ v,
    const int* __restrict__ snd, const int* __restrict__ rcv,
    const float* __restrict__ Ws0, const float* __restrict__ bs0, const float* __restrict__ Wv0,
    const float* __restrict__ Ws1, const float* __restrict__ bs1, const float* __restrict__ Wv1,
    float* __restrict__ aggMs, float* __restrict__ aggMv,
    float* __restrict__ aggAv, float* __restrict__ aggC) {
    const int e = blockIdx.x * 256 + threadIdx.x;
    if (e >= N_EDGES) return;
    const int i = snd[e], j = rcv[e];

    const float vi0 = v[i * 3 + 0], vi1 = v[i * 3 + 1], vi2 = v[i * 3 + 2];
    const float vj0 = v[j * 3 + 0], vj1 = v[j * 3 + 1], vj2 = v[j * 3 + 2];
    const float r0 = vi0 - vj0, r1 = vi1 - vj1, r2 = vi2 - vj2;
    const float nrm = sqrtf(r0 * r0 + r1 * r1 + r2 * r2);
    const float scl = 1.7320508075688772f / (nrm + 1e-8f);  // sqrt(3) * rhat
    const float a0 = r0 * scl, a1 = r1 * scl, a2 = r2 * scl;

    float xs[32];
#pragma unroll
    for (int k = 0; k < 16; k++) xs[k] = s[i * 16 + k];
#pragma unroll
    for (int k = 0; k < 16; k++) xs[16 + k] = s[j * 16 + k];
    const float di = vi0 * a0 + vi1 * a1 + vi2 * a2;
    const float dj = vj0 * a0 + vj1 * a1 + vj2 * a2;

    // ---- TPLG 0: ts = [xs(32), di, dj]; s_lin = ts@Ws0 + bs0 ----
    float sl[32];
#pragma unroll
    for (int o = 0; o < 32; o++) sl[o] = bs0[o] + di * Ws0[32 * 32 + o] + dj * Ws0[33 * 32 + o];
    float al[16];
#pragma unroll
    for (int q = 0; q < 16; q++) al[q] = 0.f;
#pragma unroll
    for (int p = 0; p < 32; p++) {
        const float x = xs[p];
#pragma unroll
        for (int o = 0; o < 32; o++) sl[o] += x * Ws0[p * 32 + o];
#pragma unroll
        for (int q = 0; q < 16; q++) al[q] += x * Wv0[p * 16 + q];
    }
    // v_lin[q] = al[q]*a + Wv0[32,q]*vi + Wv0[33,q]*vj ; gated by sigmoid(sl[q])
    float ms[16], mv0[16], mv1[16], mv2[16];
#pragma unroll
    for (int q = 0; q < 16; q++) {
        const float g = sigm(sl[q]);
        const float w32 = Wv0[32 * 16 + q], w33 = Wv0[33 * 16 + q];
        mv0[q] = (al[q] * a0 + w32 * vi0 + w33 * vj0) * g;
        mv1[q] = (al[q] * a1 + w32 * vi1 + w33 * vj1) * g;
        mv2[q] = (al[q] * a2 + w32 * vi2 + w33 * vj2) * g;
    }
#pragma unroll
    for (int p = 0; p < 16; p++) ms[p] = gelu(sl[16 + p]);

    // ---- TPLG 1: ts = [ms(16), mv[q].a (16)] ----
    float sl2[32];
#pragma unroll
    for (int o = 0; o < 32; o++) sl2[o] = bs1[o];
#pragma unroll
    for (int p = 0; p < 16; p++) {
        const float x = ms[p];
#pragma unroll
        for (int o = 0; o < 32; o++) sl2[o] += x * Ws1[p * 32 + o];
    }
#pragma unroll
    for (int q = 0; q < 16; q++) {
        const float x = mv0[q] * a0 + mv1[q] * a1 + mv2[q] * a2;
#pragma unroll
        for (int o = 0; o < 32; o++) sl2[o] += x * Ws1[(16 + q) * 32 + o];
    }
    // vector out: v2[q] = (sum_p ms[p]*Wv1[p,q])*a + sum_p mv[p]*Wv1[16+p,q]; gate+atomic
#pragma unroll
    for (int q = 0; q < 16; q++) {
        const float g = sigm(sl2[q]);
        float be = 0.f;
#pragma unroll
        for (int p = 0; p < 16; p++) be += ms[p] * Wv1[p * 16 + q];
        float u0 = be * a0, u1 = be * a1, u2 = be * a2;
#pragma unroll
        for (int p = 0; p < 16; p++) {
            const float w = Wv1[(16 + p) * 16 + q];
            u0 += mv0[p] * w; u1 += mv1[p] * w; u2 += mv2[p] * w;
        }
        unsafeAtomicAdd(&aggMv[j * 48 + q * 3 + 0], u0 * g);
        unsafeAtomicAdd(&aggMv[j * 48 + q * 3 + 1], u1 * g);
        unsafeAtomicAdd(&aggMv[j * 48 + q * 3 + 2], u2 * g);
    }
#pragma unroll
    for (int p = 0; p < 16; p++) unsafeAtomicAdd(&aggMs[j * 16 + p], gelu(sl2[16 + p]));
    unsafeAtomicAdd(&aggAv[j * 3 + 0], a0);
    unsafeAtomicAdd(&aggAv[j * 3 + 1], a1);
    unsafeAtomicAdd(&aggAv[j * 3 + 2], a2);
    unsafeAtomicAdd(&aggC[j], 1.0f);
}

__global__ __launch_bounds__(256, 1) void node_kernel(
    float* __restrict__ s, float* __restrict__ v,
    const float* __restrict__ aggMs, const float* __restrict__ aggMv,
    const float* __restrict__ aggAv, const float* __restrict__ aggC,
    const float* __restrict__ nWs, const float* __restrict__ nbs, const float* __restrict__ nWv,
    const float* __restrict__ fWs, const float* __restrict__ fbs, const float* __restrict__ fWv,
    float* __restrict__ out) {
    const int n = blockIdx.x * 256 + threadIdx.x;
    if (n >= N_NODES) return;
    const float inv = 1.0f / 319999.0f;  // 1/(E-1)
    const float cnt = aggC[n];
    const float f = inv / fmaxf(cnt, 1.0f);

    float ys[17];
#pragma unroll
    for (int c = 0; c < 16; c++) ys[c] = aggMs[n * 16 + c] * f;
    ys[16] = cnt * f;
    float yv[17][3];
#pragma unroll
    for (int d = 0; d < 16; d++) {
        yv[d][0] = aggMv[n * 48 + d * 3 + 0] * f;
        yv[d][1] = aggMv[n * 48 + d * 3 + 1] * f;
        yv[d][2] = aggMv[n * 48 + d * 3 + 2] * f;
    }
    yv[16][0] = aggAv[n * 3 + 0] * f;
    yv[16][1] = aggAv[n * 3 + 1] * f;
    yv[16][2] = aggAv[n * 3 + 2] * f;

    float ns[16];
#pragma unroll
    for (int a = 0; a < 16; a++) ns[a] = s[n * 16 + a];
    float nv0 = v[n * 3 + 0], nv1 = v[n * 3 + 1], nv2 = v[n * 3 + 2];

#pragma unroll
    for (int b = 0; b < 2; b++) {
        const float* W = nWs + b * 289 * 17;
        const float* Wv = nWv + b * 289;
        const float* bb = nbs + b * 17;
        float acc[17];
#pragma unroll
        for (int o = 0; o < 17; o++) acc[o] = bb[o];
        // ss part: p = a*17+c
#pragma unroll
        for (int a = 0; a < 16; a++) {
#pragma unroll
            for (int c = 0; c < 17; c++) {
                const float cf = ns[a] * ys[c];
                const float* Wp = W + (a * 17 + c) * 17;
#pragma unroll
                for (int o = 0; o < 17; o++) acc[o] += cf * Wp[o];
            }
        }
        // vv part: p = 272+d, coef = nv . yv[d]
#pragma unroll
        for (int d = 0; d < 17; d++) {
            const float cf = nv0 * yv[d][0] + nv1 * yv[d][1] + nv2 * yv[d][2];
            const float* Wp = W + (272 + d) * 17;
#pragma unroll
            for (int o = 0; o < 17; o++) acc[o] += cf * Wp[o];
        }
        // vector path: v_lin = sum_d (sum_a ns[a]*Wv[a*17+d]) * yv[d] + (sum_c ys[c]*Wv[272+c]) * nv
        float gam[17];
#pragma unroll
        for (int d = 0; d < 17; d++) gam[d] = 0.f;
#pragma unroll
        for (int a = 0; a < 16; a++) {
            const float x = ns[a];
#pragma unroll
            for (int d = 0; d < 17; d++) gam[d] += x * Wv[a * 17 + d];
        }
        float sc2 = 0.f;
#pragma unroll
        for (int c = 0; c < 17; c++) sc2 += ys[c] * Wv[272 + c];
        float vl0 = sc2 * nv0, vl1 = sc2 * nv1, vl2 = sc2 * nv2;
#pragma unroll
        for (int d = 0; d < 17; d++) {
            vl0 += gam[d] * yv[d][0];
            vl1 += gam[d] * yv[d][1];
            vl2 += gam[d] * yv[d][2];
        }
        const float g = sigm(acc[0]);
#pragma unroll
        for (int a = 0; a < 16; a++) ns[a] = gelu(acc[1 + a]);
        nv0 = vl0 * g; nv1 = vl1 * g; nv2 = vl2 * g;
    }
    // final linear back to irreps_in + residual
    float so[16];
#pragma unroll
    for (int a = 0; a < 16; a++) so[a] = fbs[a];
#pragma unroll
    for (int p = 0; p < 16; p++) {
        const float x = ns[p];
#pragma unroll
        for (int a = 0; a < 16; a++) so[a] += x * fWs[p * 16 + a];
    }
    const float fw = fWv[0];
    float sn[16];
#pragma unroll
    for (int a = 0; a < 16; a++) { sn[a] = s[n * 16 + a] + so[a]; s[n * 16 + a] = sn[a]; }
    const float w0 = v[n * 3 + 0] + nv0 * fw;
    const float w1 = v[n * 3 + 1] + nv1 * fw;
    const float w2 = v[n * 3 + 2] + nv2 * fw;
    v[n * 3 + 0] = w0; v[n * 3 + 1] = w1; v[n * 3 + 2] = w2;
    if (out) {
#pragma unroll
        for (int a = 0; a < 16; a++) out[n * 19 + a] = sn[a];
        out[n * 19 + 16] = w0;
        out[n * 19 + 17] = w1;
        out[n * 19 + 18] = w2;
    }
}

extern "C" void kernel_launch(void* const* d_in, const int* in_sizes, int n_in,
                              void* d_out, int out_size, void* d_ws, size_t ws_size,
                              hipStream_t stream) {
    const float* node_scalars = (const float*)d_in[0];
    const float* node_pos = (const float*)d_in[1];
    const int* senders = (const int*)d_in[2];
    const int* receivers = (const int*)d_in[3];
    const float* eWs0 = (const float*)d_in[4];
    const float* ebs0 = (const float*)d_in[5];
    const float* eWv0 = (const float*)d_in[6];
    const float* eWs1 = (const float*)d_in[7];
    const float* ebs1 = (const float*)d_in[8];
    const float* eWv1 = (const float*)d_in[9];
    const float* nWs = (const float*)d_in[10];
    const float* nbs = (const float*)d_in[11];
    const float* nWv = (const float*)d_in[12];
    const float* fWs = (const float*)d_in[13];
    const float* fbs = (const float*)d_in[14];
    const float* fWv = (const float*)d_in[15];

    float* ws = (float*)d_ws;
    float* s = ws;                        // N*16
    float* v = s + N_NODES * 16;          // N*3
    float* agg = v + N_NODES * 3;         // N*68 contiguous
    float* aggMs = agg;                   // N*16
    float* aggMv = aggMs + N_NODES * 16;  // N*48
    float* aggAv = aggMv + N_NODES * 48;  // N*3
    float* aggC = aggAv + N_NODES * 3;    // N
    float* out = (float*)d_out;

    init_kernel<<<(N_NODES * 16 + 255) / 256, 256, 0, stream>>>(node_scalars, node_pos, s, v);
    for (int t = 0; t < 3; t++) {
        hipMemsetAsync(agg, 0, (size_t)N_NODES * 68 * sizeof(float), stream);
        edge_kernel<<<(N_EDGES + 255) / 256, 256, 0, stream>>>(
            s, v, senders, receivers,
            eWs0 + t * 34 * 32, ebs0 + t * 32, eWv0 + t * 34 * 16,
            eWs1 + t * 32 * 32, ebs1 + t * 32, eWv1 + t * 32 * 16,
            aggMs, aggMv, aggAv, aggC);
        node_kernel<<<(N_NODES + 255) / 256, 256, 0, stream>>>(
            s, v, aggMs, aggMv, aggAv, aggC,
            nWs + t * 2 * 289 * 17, nbs + t * 2 * 17, nWv + t * 2 * 289,
            fWs + t * 256, fbs + t * 16, fWv + t,
            (t == 2) ? out : nullptr);
    }
}

// Round 2
// 1035.288 us; speedup vs baseline: 3.7629x; 3.7629x over previous
//
#include <hip/hip_runtime.h>

#define N_NODES 20000
#define N_EDGES 320000
#define CH 68       // agg row stride (67 used + 1 pad)
#define LDSROW 69   // LDS row stride: 69 mod 32 = 5, coprime -> only 2-way aliasing (free)

__device__ __forceinline__ float sigm(float x) { return 1.0f / (1.0f + __expf(-x)); }
// jax.nn.gelu approximate=True == x*sigmoid(1.5957691*(x+0.044715x^3))
__device__ __forceinline__ float gelu(float x) {
    return x * sigm(1.5957691216057308f * (x + 0.044715f * x * x * x));
}

__global__ void init_kernel(const float* __restrict__ s0, const float* __restrict__ p0,
                            float* __restrict__ s, float* __restrict__ v) {
    int idx = blockIdx.x * 256 + threadIdx.x;
    if (idx < N_NODES * 16) s[idx] = s0[idx];
    if (idx < N_NODES * 3) v[idx] = p0[idx];
}

__global__ void count_kernel(const int* __restrict__ rcv, float* __restrict__ cnt) {
    int e = blockIdx.x * 256 + threadIdx.x;
    if (e < N_EDGES) unsafeAtomicAdd(&cnt[rcv[e]], 1.0f);
}

__global__ __launch_bounds__(64) void edge_kernel(
    const float* __restrict__ s, const float* __restrict__ v,
    const int* __restrict__ snd, const int* __restrict__ rcv,
    const float* __restrict__ Ws0, const float* __restrict__ bs0, const float* __restrict__ Wv0,
    const float* __restrict__ Ws1, const float* __restrict__ bs1, const float* __restrict__ Wv1,
    float* __restrict__ agg) {
    __shared__ float lds[64 * LDSROW];
    const int lane = threadIdx.x;
    const int e = blockIdx.x * 64 + lane;  // grid exactly covers N_EDGES (5000*64)
    const int i = snd[e], j = rcv[e];

    const float vi0 = v[i * 3 + 0], vi1 = v[i * 3 + 1], vi2 = v[i * 3 + 2];
    const float vj0 = v[j * 3 + 0], vj1 = v[j * 3 + 1], vj2 = v[j * 3 + 2];
    const float r0 = vi0 - vj0, r1 = vi1 - vj1, r2 = vi2 - vj2;
    const float nrm = sqrtf(r0 * r0 + r1 * r1 + r2 * r2);
    const float scl = 1.7320508075688772f / (nrm + 1e-8f);  // sqrt(3) * rhat
    const float a0 = r0 * scl, a1 = r1 * scl, a2 = r2 * scl;

    float xs[32];
#pragma unroll
    for (int k = 0; k < 16; k++) xs[k] = s[i * 16 + k];
#pragma unroll
    for (int k = 0; k < 16; k++) xs[16 + k] = s[j * 16 + k];
    const float di = vi0 * a0 + vi1 * a1 + vi2 * a2;
    const float dj = vj0 * a0 + vj1 * a1 + vj2 * a2;

    // ---- TPLG 0 ----
    float sl[32];
#pragma unroll
    for (int o = 0; o < 32; o++) sl[o] = bs0[o] + di * Ws0[32 * 32 + o] + dj * Ws0[33 * 32 + o];
    float al[16];
#pragma unroll
    for (int q = 0; q < 16; q++) al[q] = 0.f;
#pragma unroll
    for (int p = 0; p < 32; p++) {
        const float x = xs[p];
#pragma unroll
        for (int o = 0; o < 32; o++) sl[o] += x * Ws0[p * 32 + o];
#pragma unroll
        for (int q = 0; q < 16; q++) al[q] += x * Wv0[p * 16 + q];
    }
    float ms[16], mv0[16], mv1[16], mv2[16];
#pragma unroll
    for (int q = 0; q < 16; q++) {
        const float g = sigm(sl[q]);
        const float w32 = Wv0[32 * 16 + q], w33 = Wv0[33 * 16 + q];
        mv0[q] = (al[q] * a0 + w32 * vi0 + w33 * vj0) * g;
        mv1[q] = (al[q] * a1 + w32 * vi1 + w33 * vj1) * g;
        mv2[q] = (al[q] * a2 + w32 * vi2 + w33 * vj2) * g;
    }
#pragma unroll
    for (int p = 0; p < 16; p++) ms[p] = gelu(sl[16 + p]);

    // ---- TPLG 1 ----
    float sl2[32];
#pragma unroll
    for (int o = 0; o < 32; o++) sl2[o] = bs1[o];
#pragma unroll
    for (int p = 0; p < 16; p++) {
        const float x = ms[p];
#pragma unroll
        for (int o = 0; o < 32; o++) sl2[o] += x * Ws1[p * 32 + o];
    }
#pragma unroll
    for (int q = 0; q < 16; q++) {
        const float x = mv0[q] * a0 + mv1[q] * a1 + mv2[q] * a2;
#pragma unroll
        for (int o = 0; o < 32; o++) sl2[o] += x * Ws1[(16 + q) * 32 + o];
    }

    float* row = &lds[lane * LDSROW];
#pragma unroll
    for (int q = 0; q < 16; q++) {
        const float g = sigm(sl2[q]);
        float be = 0.f;
#pragma unroll
        for (int p = 0; p < 16; p++) be += ms[p] * Wv1[p * 16 + q];
        float u0 = be * a0, u1 = be * a1, u2 = be * a2;
#pragma unroll
        for (int p = 0; p < 16; p++) {
            const float w = Wv1[(16 + p) * 16 + q];
            u0 += mv0[p] * w; u1 += mv1[p] * w; u2 += mv2[p] * w;
        }
        row[16 + q * 3 + 0] = u0 * g;
        row[16 + q * 3 + 1] = u1 * g;
        row[16 + q * 3 + 2] = u2 * g;
    }
#pragma unroll
    for (int p = 0; p < 16; p++) row[p] = gelu(sl2[16 + p]);
    row[64] = a0; row[65] = a1; row[66] = a2;
    __syncthreads();

    // wave-coalesced atomic flush: one node per iteration, lane = channel
#pragma unroll 4
    for (int k = 0; k < 64; k++) {
        const int jj = __shfl(j, k);
        const float val = lds[k * LDSROW + lane];
        unsafeAtomicAdd(&agg[jj * CH + lane], val);
        if (lane < 3) {
            const float v2 = lds[k * LDSROW + 64 + lane];
            unsafeAtomicAdd(&agg[jj * CH + 64 + lane], v2);
        }
    }
}

__global__ __launch_bounds__(64, 1) void node_kernel(
    float* __restrict__ s, float* __restrict__ v,
    const float* __restrict__ agg, const float* __restrict__ cntb,
    const float* __restrict__ nWs, const float* __restrict__ nbs, const float* __restrict__ nWv,
    const float* __restrict__ fWs, const float* __restrict__ fbs, const float* __restrict__ fWv,
    float* __restrict__ out) {
    const int n = blockIdx.x * 64 + threadIdx.x;
    if (n >= N_NODES) return;
    const float inv = 1.0f / 319999.0f;  // 1/(E-1)
    const float cnt = cntb[n];
    const float f = inv / fmaxf(cnt, 1.0f);
    const float* ag = agg + n * CH;

    float ys[17];
#pragma unroll
    for (int c = 0; c < 16; c++) ys[c] = ag[c] * f;
    ys[16] = cnt * f;
    float yv[17][3];
#pragma unroll
    for (int d = 0; d < 16; d++) {
        yv[d][0] = ag[16 + d * 3 + 0] * f;
        yv[d][1] = ag[16 + d * 3 + 1] * f;
        yv[d][2] = ag[16 + d * 3 + 2] * f;
    }
    yv[16][0] = ag[64] * f;
    yv[16][1] = ag[65] * f;
    yv[16][2] = ag[66] * f;

    float ns[16];
#pragma unroll
    for (int a = 0; a < 16; a++) ns[a] = s[n * 16 + a];
    float nv0 = v[n * 3 + 0], nv1 = v[n * 3 + 1], nv2 = v[n * 3 + 2];

#pragma unroll
    for (int b = 0; b < 2; b++) {
        const float* W = nWs + b * 289 * 17;
        const float* Wv = nWv + b * 289;
        const float* bb = nbs + b * 17;
        float acc[17];
#pragma unroll
        for (int o = 0; o < 17; o++) acc[o] = bb[o];
#pragma unroll
        for (int a = 0; a < 16; a++) {
#pragma unroll
            for (int c = 0; c < 17; c++) {
                const float cf = ns[a] * ys[c];
                const float* Wp = W + (a * 17 + c) * 17;
#pragma unroll
                for (int o = 0; o < 17; o++) acc[o] += cf * Wp[o];
            }
        }
#pragma unroll
        for (int d = 0; d < 17; d++) {
            const float cf = nv0 * yv[d][0] + nv1 * yv[d][1] + nv2 * yv[d][2];
            const float* Wp = W + (272 + d) * 17;
#pragma unroll
            for (int o = 0; o < 17; o++) acc[o] += cf * Wp[o];
        }
        float gam[17];
#pragma unroll
        for (int d = 0; d < 17; d++) gam[d] = 0.f;
#pragma unroll
        for (int a = 0; a < 16; a++) {
            const float x = ns[a];
#pragma unroll
            for (int d = 0; d < 17; d++) gam[d] += x * Wv[a * 17 + d];
        }
        float sc2 = 0.f;
#pragma unroll
        for (int c = 0; c < 17; c++) sc2 += ys[c] * Wv[272 + c];
        float vl0 = sc2 * nv0, vl1 = sc2 * nv1, vl2 = sc2 * nv2;
#pragma unroll
        for (int d = 0; d < 17; d++) {
            vl0 += gam[d] * yv[d][0];
            vl1 += gam[d] * yv[d][1];
            vl2 += gam[d] * yv[d][2];
        }
        const float g = sigm(acc[0]);
#pragma unroll
        for (int a = 0; a < 16; a++) ns[a] = gelu(acc[1 + a]);
        nv0 = vl0 * g; nv1 = vl1 * g; nv2 = vl2 * g;
    }
    float so[16];
#pragma unroll
    for (int a = 0; a < 16; a++) so[a] = fbs[a];
#pragma unroll
    for (int p = 0; p < 16; p++) {
        const float x = ns[p];
#pragma unroll
        for (int a = 0; a < 16; a++) so[a] += x * fWs[p * 16 + a];
    }
    const float fw = fWv[0];
    float sn[16];
#pragma unroll
    for (int a = 0; a < 16; a++) { sn[a] = s[n * 16 + a] + so[a]; s[n * 16 + a] = sn[a]; }
    const float w0 = v[n * 3 + 0] + nv0 * fw;
    const float w1 = v[n * 3 + 1] + nv1 * fw;
    const float w2 = v[n * 3 + 2] + nv2 * fw;
    v[n * 3 + 0] = w0; v[n * 3 + 1] = w1; v[n * 3 + 2] = w2;
    if (out) {
#pragma unroll
        for (int a = 0; a < 16; a++) out[n * 19 + a] = sn[a];
        out[n * 19 + 16] = w0;
        out[n * 19 + 17] = w1;
        out[n * 19 + 18] = w2;
    }
}

extern "C" void kernel_launch(void* const* d_in, const int* in_sizes, int n_in,
                              void* d_out, int out_size, void* d_ws, size_t ws_size,
                              hipStream_t stream) {
    const float* node_scalars = (const float*)d_in[0];
    const float* node_pos = (const float*)d_in[1];
    const int* senders = (const int*)d_in[2];
    const int* receivers = (const int*)d_in[3];
    const float* eWs0 = (const float*)d_in[4];
    const float* ebs0 = (const float*)d_in[5];
    const float* eWv0 = (const float*)d_in[6];
    const float* eWs1 = (const float*)d_in[7];
    const float* ebs1 = (const float*)d_in[8];
    const float* eWv1 = (const float*)d_in[9];
    const float* nWs = (const float*)d_in[10];
    const float* nbs = (const float*)d_in[11];
    const float* nWv = (const float*)d_in[12];
    const float* fWs = (const float*)d_in[13];
    const float* fbs = (const float*)d_in[14];
    const float* fWv = (const float*)d_in[15];

    float* ws = (float*)d_ws;
    float* s = ws;                        // N*16
    float* v = s + N_NODES * 16;          // N*3
    float* agg = v + N_NODES * 3;         // N*CH, 64B-aligned (offset 1,520,000 B)
    float* cnt = agg + N_NODES * CH;      // N
    float* out = (float*)d_out;

    init_kernel<<<(N_NODES * 16 + 255) / 256, 256, 0, stream>>>(node_scalars, node_pos, s, v);
    hipMemsetAsync(cnt, 0, (size_t)N_NODES * sizeof(float), stream);
    count_kernel<<<(N_EDGES + 255) / 256, 256, 0, stream>>>(receivers, cnt);
    for (int t = 0; t < 3; t++) {
        hipMemsetAsync(agg, 0, (size_t)N_NODES * CH * sizeof(float), stream);
        edge_kernel<<<N_EDGES / 64, 64, 0, stream>>>(
            s, v, senders, receivers,
            eWs0 + t * 34 * 32, ebs0 + t * 32, eWv0 + t * 34 * 16,
            eWs1 + t * 32 * 32, ebs1 + t * 32, eWv1 + t * 32 * 16,
            agg);
        node_kernel<<<(N_NODES + 63) / 64, 64, 0, stream>>>(
            s, v, agg, cnt,
            nWs + t * 2 * 289 * 17, nbs + t * 2 * 17, nWv + t * 2 * 289,
            fWs + t * 256, fbs + t * 16, fWv + t,
            (t == 2) ? out : nullptr);
    }
}